// Round 9
// baseline (450.359 us; speedup 1.0000x reference)
//
#include <hip/hip_runtime.h>
#include <hip/hip_bf16.h>

typedef unsigned short u16;
typedef __attribute__((ext_vector_type(8))) short short8;
typedef __attribute__((ext_vector_type(4))) short short4v;
typedef __attribute__((ext_vector_type(4))) float f32x4;
typedef __attribute__((ext_vector_type(16))) float f32x16;

#define HEADS 20
#define HD 64
#define BB 8
#define SQ 4096
#define HDIM 1280
#define SKV 109
#define CDIM 768
#define SKV_PAD 128
#define SKV_T 112

#define SBAR() asm volatile("s_barrier" ::: "memory")

static __device__ __forceinline__ u16 f2bf(float x) {
  union { __hip_bfloat16 h; u16 u; } cv;
  cv.h = __float2bfloat16(x);
  return cv.u;
}

// async global->LDS, 16B per lane (dest = wave-uniform base + lane*16).
static __device__ __forceinline__ void gll16(const void* g, void* l) {
  __builtin_amdgcn_global_load_lds(
      (const __attribute__((address_space(1))) unsigned int*)g,
      (__attribute__((address_space(3))) unsigned int*)l, 16, 0, 0);
}

// ---- prep: out[n][k] = bf16(W[k][n] * scale)  (W is K x N row-major)
__global__ __launch_bounds__(256) void tcvt(const float* __restrict__ W,
                                            u16* __restrict__ out, int K, int N,
                                            float scale) {
  __shared__ float t[32][33];
  int tx = threadIdx.x & 31, ty = threadIdx.x >> 5;
  int n0 = blockIdx.x * 32, k0 = blockIdx.y * 32;
#pragma unroll
  for (int i = 0; i < 32; i += 8)
    t[ty + i][tx] = W[(size_t)(k0 + ty + i) * N + n0 + tx];
  __syncthreads();
#pragma unroll
  for (int i = 0; i < 32; i += 8)
    out[(size_t)(n0 + ty + i) * K + k0 + tx] = f2bf(t[tx][ty + i] * scale);
}

// ---- prep: encoder states f32 (8,109,768) -> bf16 (8,128,768), zero pad rows
__global__ __launch_bounds__(256) void ehs_prep(const float* __restrict__ e,
                                                u16* __restrict__ out) {
  int idx = blockIdx.x * 256 + threadIdx.x;
  if (idx >= BB * SKV_PAD * CDIM / 4) return;
  int c4 = idx * 4;
  int b = c4 / (SKV_PAD * CDIM);
  int rem = c4 - b * (SKV_PAD * CDIM);
  int s = rem / CDIM;
  int c = rem - s * CDIM;
  short4v o = {0, 0, 0, 0};
  if (s < SKV) {
    f32x4 v = *(const f32x4*)(e + ((size_t)b * SKV + s) * CDIM + c);
#pragma unroll
    for (int j = 0; j < 4; j++) o[j] = (short)f2bf(v[j]);
  }
  *(short4v*)&out[c4] = o;
}

// ---- prep: hidden_states f32 -> bf16 (vectorized 8/thread, grid-stride)
__global__ __launch_bounds__(256) void hscvt(const float* __restrict__ in,
                                             u16* __restrict__ out) {
  const size_t total = (size_t)BB * SQ * HDIM;
  size_t step = (size_t)gridDim.x * 256 * 8;
  for (size_t i = ((size_t)blockIdx.x * 256 + threadIdx.x) * 8; i < total;
       i += step) {
    f32x4 a = *(const f32x4*)(in + i);
    f32x4 b = *(const f32x4*)(in + i + 4);
    short8 o;
#pragma unroll
    for (int j = 0; j < 4; j++) {
      o[j] = (short)f2bf(a[j]);
      o[j + 4] = (short)f2bf(b[j]);
    }
    *(short8*)&out[i] = o;
  }
}

// ============ 128x256 tile, BK=32, 3-buffer counted-vmcnt GEMM ===============
// r8 skeleton unchanged; compute swapped to v_mfma_f32_32x32x16_bf16.
// 8 waves (2M x 4N), wave owns 64x64 -> 2x2 frags of 32x32, acc = 64 AGPR.
// Per tile: stage t+2 (3 gll16) -> 8 plain ds_read_b128 -> 8 MFMA 32x32x16 ->
// vmcnt(3) -> s_barrier. Swizzle chunk ^= (row>>1)&3 (lane-constant
// ((lane&31)>>1)&3 for 32-row frags), bank-balanced (4 dwords/bank exact).
// C/D layout (m74/m101): col = lane&31, row = (reg&3)+8*(reg>>2)+4*(lane>>5).
// MODE 0: bf16 row-major out. MODE 3: f32 out + bias + residual.

template <int MODE>
__global__ __launch_bounds__(512, 4)
void gemm_v2(const u16* __restrict__ A, const u16* __restrict__ Bt,
             void* __restrict__ outp, int K, int ntn,
             const float* __restrict__ bias, const float* __restrict__ resid) {
  // per buf: A elems [0,4096) = 128x32, B elems [4096,12288) = 256x32
  __shared__ u16 lds[3][12288];
  const int tid = threadIdx.x;
  const int wid = tid >> 6, lane = tid & 63;
  const int wm = wid >> 2, wn = wid & 3;
  const int l31 = lane & 31, hi = lane >> 5;

  const int nwg = gridDim.x;
  const int orig = blockIdx.x;
  const int wg = (orig & 7) * (nwg >> 3) + (orig >> 3);  // XCD swizzle
  const int mt = wg / ntn, nt = wg - mt * ntn;
  const int row0 = mt * 128, col0 = nt * 256;

  const u16* Ag = A + (size_t)row0 * K;
  const u16* Bg = Bt + (size_t)col0 * K;
  const int NT = K >> 5;

  // swizzled lane-constant read chunks: kw in {0,1} -> chunk (kw*2+hi)^cswz
  const int cswz = (l31 >> 1) & 3;
  const int cx0 = ((0 * 2 + hi) ^ cswz) * 8;  // k window 0..15
  const int cx1 = ((1 * 2 + hi) ^ cswz) * 8;  // k window 16..31

  // staging: A = 512 chunks (1/thread), B = 1024 chunks (2/thread)
  const int sa_row = tid >> 2;
  const int sa_sc = (tid & 3) ^ ((tid >> 3) & 3);
  const int sb_row1 = (tid + 512) >> 2;
  const int sb_sc1 = ((tid + 512) & 3) ^ (((tid + 512) >> 3) & 3);

  f32x16 acc[2][2] = {};

  auto stage = [&](int buf, int kt) {
    gll16(Ag + (size_t)sa_row * K + kt + sa_sc * 8, &lds[buf][tid * 8]);
    gll16(Bg + (size_t)sa_row * K + kt + sa_sc * 8, &lds[buf][4096 + tid * 8]);
    gll16(Bg + (size_t)sb_row1 * K + kt + sb_sc1 * 8,
          &lds[buf][4096 + (tid + 512) * 8]);
  };

  // prologue: stage tiles 0,1 (6 instrs); vmcnt(3) retires tile 0
  stage(0, 0);
  stage(1, 32);
  asm volatile("s_waitcnt vmcnt(3)" ::: "memory");
  SBAR();

  int buf = 0;
  for (int t = 0; t < NT; ++t) {
    int nb = buf + 2;
    if (nb >= 3) nb -= 3;
    if (t + 2 < NT) stage(nb, (t + 2) * 32);

    short8 a[2][2], b[2][2];
#pragma unroll
    for (int fa = 0; fa < 2; ++fa) {
      a[fa][0] = *(short8*)&lds[buf][(wm * 64 + fa * 32 + l31) * 32 + cx0];
      a[fa][1] = *(short8*)&lds[buf][(wm * 64 + fa * 32 + l31) * 32 + cx1];
    }
#pragma unroll
    for (int fb = 0; fb < 2; ++fb) {
      b[fb][0] = *(short8*)&lds[buf][4096 + (wn * 64 + fb * 32 + l31) * 32 + cx0];
      b[fb][1] = *(short8*)&lds[buf][4096 + (wn * 64 + fb * 32 + l31) * 32 + cx1];
    }

    __builtin_amdgcn_s_setprio(1);
#pragma unroll
    for (int fa = 0; fa < 2; ++fa)
#pragma unroll
      for (int fb = 0; fb < 2; ++fb)
#pragma unroll
        for (int kw = 0; kw < 2; ++kw)
          acc[fa][fb] = __builtin_amdgcn_mfma_f32_32x32x16_bf16(
              a[fa][kw], b[fb][kw], acc[fa][fb], 0, 0, 0);
    __builtin_amdgcn_s_setprio(0);

    if (t < NT - 2)
      asm volatile("s_waitcnt vmcnt(3)" ::: "memory");
    else
      asm volatile("s_waitcnt vmcnt(0)" ::: "memory");
    SBAR();
    buf = (buf + 1 == 3) ? 0 : buf + 1;
  }

  // epilogue: row = row0+wm*64+fa*32+(reg&3)+8*(reg>>2)+4*hi, col = col0+wn*64+fb*32+l31
  if constexpr (MODE == 0) {
    u16* O = (u16*)outp;
#pragma unroll
    for (int fa = 0; fa < 2; ++fa)
#pragma unroll
      for (int fb = 0; fb < 2; ++fb)
#pragma unroll
        for (int reg = 0; reg < 16; ++reg) {
          size_t m = row0 + wm * 64 + fa * 32 + (reg & 3) + 8 * (reg >> 2) + 4 * hi;
          O[m * HDIM + col0 + wn * 64 + fb * 32 + l31] = f2bf(acc[fa][fb][reg]);
        }
  } else {
    float* O = (float*)outp;
#pragma unroll
    for (int fa = 0; fa < 2; ++fa)
#pragma unroll
      for (int fb = 0; fb < 2; ++fb)
#pragma unroll
        for (int reg = 0; reg < 16; ++reg) {
          size_t m = row0 + wm * 64 + fa * 32 + (reg & 3) + 8 * (reg >> 2) + 4 * hi;
          int col = col0 + wn * 64 + fb * 32 + l31;
          size_t idx = m * HDIM + col;
          O[idx] = acc[fa][fb][reg] + bias[col] + resid[idx];
        }
  }
}

// ---- m97-structure 128x128 GEMM, kept for the small K/V projections.
// MODE 1: K-heads layout. MODE 2: V^T layout.
template <int MODE>
__global__ __launch_bounds__(256, 4)
void gemm_glds(const u16* __restrict__ A, const u16* __restrict__ Bt,
               void* __restrict__ outp, int K, int ntn) {
  __shared__ u16 Alds[128 * 32];
  __shared__ u16 Blds[128 * 32];
  const int tid = threadIdx.x;
  const int wid = tid >> 6, lane = tid & 63;
  const int wm = wid >> 1, wn = wid & 1;
  const int g = lane >> 4, r = lane & 15;

  const int nwg = gridDim.x;
  const int orig = blockIdx.x;
  const int wg = (orig & 7) * (nwg >> 3) + (orig >> 3);
  const int mt = wg / ntn, nt = wg - mt * ntn;
  const int row0 = mt * 128, col0 = nt * 128;
  const int erow = tid >> 2, ecol = (tid & 3) * 8;

  f32x4 acc[4][4] = {};

  for (int kt = 0; kt < K; kt += 32) {
    const u16* ag = A + (size_t)(row0 + erow) * K + kt + ecol;
    const u16* bg = Bt + (size_t)(col0 + erow) * K + kt + ecol;
    gll16(ag, &Alds[erow * 32 + ecol]);
    gll16(ag + (size_t)64 * K, &Alds[(erow + 64) * 32 + ecol]);
    gll16(bg, &Blds[erow * 32 + ecol]);
    gll16(bg + (size_t)64 * K, &Blds[(erow + 64) * 32 + ecol]);
    __syncthreads();

    short8 afr[4], bfr[4];
#pragma unroll
    for (int mi = 0; mi < 4; mi++)
      afr[mi] = *(short8*)&Alds[(wm * 64 + mi * 16 + r) * 32 + g * 8];
#pragma unroll
    for (int ni = 0; ni < 4; ni++)
      bfr[ni] = *(short8*)&Blds[(wn * 64 + ni * 16 + r) * 32 + g * 8];
#pragma unroll
    for (int mi = 0; mi < 4; mi++)
#pragma unroll
      for (int ni = 0; ni < 4; ni++)
        acc[mi][ni] = __builtin_amdgcn_mfma_f32_16x16x32_bf16(afr[mi], bfr[ni],
                                                              acc[mi][ni], 0, 0, 0);
    __syncthreads();
  }

  u16* O = (u16*)outp;
#pragma unroll
  for (int mi = 0; mi < 4; mi++)
#pragma unroll
    for (int i = 0; i < 4; i++) {
      int m = row0 + wm * 64 + mi * 16 + g * 4 + i;
      int b = m >> 7, skv = m & 127;
#pragma unroll
      for (int ni = 0; ni < 4; ni++) {
        int col = col0 + wn * 64 + ni * 16 + r;
        int hh = col >> 6, d = col & 63;
        size_t addr;
        if constexpr (MODE == 1)
          addr = (((size_t)b * HEADS + hh) * SKV_PAD + skv) * HD + d;
        else
          addr = (((size_t)b * HEADS + hh) * HD + d) * SKV_PAD + skv;
        O[addr] = f2bf(acc[mi][ni][i]);
      }
    }
}

// ---- fused attention: per block = 64 q-rows of one (b,h); 4 waves x 16 rows.
__global__ __launch_bounds__(256, 2)
void attn_kernel(const u16* __restrict__ q, const u16* __restrict__ kh,
                 const u16* __restrict__ vt, u16* __restrict__ o) {
  __shared__ u16 Klds[SKV_T * 72];
  __shared__ u16 Vlds[HD * 136];
  __shared__ u16 Plds[4 * 16 * 136];
  const int tid = threadIdx.x;
  const int wid = tid >> 6, lane = tid & 63;
  const int g = lane >> 4, r = lane & 15;
  const int qt = blockIdx.x;
  const int bh = blockIdx.y;
  const int b = bh / HEADS, h = bh - b * HEADS;

  const u16* kg = kh + (size_t)bh * SKV_PAD * HD;
  for (int i = tid; i < SKV_T * 8; i += 256) {
    int row = i >> 3, c = (i & 7) * 8;
    *(short8*)&Klds[row * 72 + c] = *(const short8*)(kg + row * HD + c);
  }
  const u16* vg = vt + (size_t)bh * HD * SKV_PAD;
  for (int i = tid; i < HD * 16; i += 256) {
    int row = i >> 4, c = (i & 15) * 8;
    *(short8*)&Vlds[row * 136 + c] = *(const short8*)(vg + row * SKV_PAD + c);
  }
  __syncthreads();

  const u16* qg = q + ((size_t)b * SQ + qt * 64 + wid * 16 + r) * HDIM + h * HD + g * 8;
  short8 aq0 = *(const short8*)(qg);
  short8 aq1 = *(const short8*)(qg + 32);

  f32x4 s[7];
#pragma unroll
  for (int nf = 0; nf < 7; nf++) {
    f32x4 z = {0.f, 0.f, 0.f, 0.f};
    short8 k0 = *(short8*)&Klds[(nf * 16 + r) * 72 + g * 8];
    short8 k1 = *(short8*)&Klds[(nf * 16 + r) * 72 + 32 + g * 8];
    z = __builtin_amdgcn_mfma_f32_16x16x32_bf16(aq0, k0, z, 0, 0, 0);
    z = __builtin_amdgcn_mfma_f32_16x16x32_bf16(aq1, k1, z, 0, 0, 0);
    s[nf] = z;
  }

  {
    short4v z = {0, 0, 0, 0};
    *(short4v*)&Plds[(wid * 16 + r) * 136 + 112 + g * 4] = z;
  }

#pragma unroll
  for (int i = 0; i < 4; i++) {
    float pv[7];
    float mx = -1e30f;
#pragma unroll
    for (int nf = 0; nf < 7; nf++) {
      float v = s[nf][i];
      if (nf == 6 && r >= 13) v = -1e30f;
      pv[nf] = v;
      mx = fmaxf(mx, v);
    }
#pragma unroll
    for (int d = 1; d < 16; d <<= 1) mx = fmaxf(mx, __shfl_xor(mx, d, 64));
    float sum = 0.f;
#pragma unroll
    for (int nf = 0; nf < 7; nf++) {
      float e = (nf == 6 && r >= 13) ? 0.f : __expf(pv[nf] - mx);
      pv[nf] = e;
      sum += e;
    }
#pragma unroll
    for (int d = 1; d < 16; d <<= 1) sum += __shfl_xor(sum, d, 64);
    float is = 1.f / sum;
#pragma unroll
    for (int nf = 0; nf < 7; nf++)
      Plds[(wid * 16 + g * 4 + i) * 136 + nf * 16 + r] = f2bf(pv[nf] * is);
  }
  __syncthreads();

  f32x4 oacc[4] = {};
#pragma unroll
  for (int kk = 0; kk < 4; kk++) {
    short8 ap = *(short8*)&Plds[(wid * 16 + r) * 136 + kk * 32 + g * 8];
#pragma unroll
    for (int nf = 0; nf < 4; nf++) {
      short8 bv = *(short8*)&Vlds[(nf * 16 + r) * 136 + kk * 32 + g * 8];
      oacc[nf] = __builtin_amdgcn_mfma_f32_16x16x32_bf16(ap, bv, oacc[nf], 0, 0, 0);
    }
  }
  u16* og = o + ((size_t)b * SQ + qt * 64 + wid * 16) * HDIM + h * HD;
#pragma unroll
  for (int nf = 0; nf < 4; nf++)
#pragma unroll
    for (int i = 0; i < 4; i++)
      og[(size_t)(g * 4 + i) * HDIM + nf * 16 + r] = f2bf(oacc[nf][i]);
}

extern "C" void kernel_launch(void* const* d_in, const int* in_sizes, int n_in,
                              void* d_out, int out_size, void* d_ws, size_t ws_size,
                              hipStream_t stream) {
  const float* hs  = (const float*)d_in[0];
  const float* ehs = (const float*)d_in[1];
  const float* Wq  = (const float*)d_in[2];
  const float* Wk  = (const float*)d_in[3];
  const float* Wv  = (const float*)d_in[4];
  const float* Wo  = (const float*)d_in[5];
  const float* bo  = (const float*)d_in[6];

  char* ws = (char*)d_ws;
  size_t off = 0;
  auto alloc = [&](size_t elems) {
    u16* p = (u16*)(ws + off);
    off += ((elems * 2 + 255) / 256) * 256;
    return p;
  };
  u16* wqt  = alloc((size_t)HDIM * HDIM);
  u16* wot  = alloc((size_t)HDIM * HDIM);
  u16* wkt  = alloc((size_t)HDIM * CDIM);
  u16* wvt  = alloc((size_t)HDIM * CDIM);
  u16* ehsp = alloc((size_t)BB * SKV_PAD * CDIM);
  u16* khb  = alloc((size_t)BB * HEADS * SKV_PAD * HD);
  u16* vtb  = alloc((size_t)BB * HEADS * HD * SKV_PAD);
  u16* qb   = alloc((size_t)BB * SQ * HDIM);
  u16* ao   = alloc((size_t)BB * SQ * HDIM);
  u16* hsb  = ao;  // alias: hsb dead before attention writes ao

  tcvt<<<dim3(HDIM / 32, HDIM / 32), 256, 0, stream>>>(Wq, wqt, HDIM, HDIM, 0.125f);
  tcvt<<<dim3(HDIM / 32, CDIM / 32), 256, 0, stream>>>(Wk, wkt, CDIM, HDIM, 1.0f);
  tcvt<<<dim3(HDIM / 32, CDIM / 32), 256, 0, stream>>>(Wv, wvt, CDIM, HDIM, 1.0f);
  tcvt<<<dim3(HDIM / 32, HDIM / 32), 256, 0, stream>>>(Wo, wot, HDIM, HDIM, 1.0f);
  ehs_prep<<<dim3((BB * SKV_PAD * CDIM / 4 + 255) / 256), 256, 0, stream>>>(ehs, ehsp);
  hscvt<<<dim3(2048), 256, 0, stream>>>(hs, hsb);

  // K,V projections (M = 1024 padded rows; grid 80 % 8 == 0)
  gemm_glds<1><<<dim3(80), 256, 0, stream>>>(ehsp, wkt, khb, CDIM, 10);
  gemm_glds<2><<<dim3(80), 256, 0, stream>>>(ehsp, wvt, vtb, CDIM, 10);
  // Q projection: 128x256 3-buf counted-vmcnt, 32x32x16 MFMA (grid 1280 % 8 == 0)
  gemm_v2<0><<<dim3(1280), 512, 0, stream>>>(hsb, wqt, qb, HDIM, 5, nullptr, nullptr);
  // attention
  attn_kernel<<<dim3(SQ / 64, BB * HEADS), 256, 0, stream>>>(qb, khb, vtb, ao);
  // output projection + bias + f32 residual
  gemm_v2<3><<<dim3(1280), 512, 0, stream>>>(ao, wot, (void*)d_out, HDIM, 5, bo, hs);
}